// Round 2
// baseline (48603.751 us; speedup 1.0000x reference)
//
#include <hip/hip_runtime.h>

#define SEQ 32768
#define ISZ 256
#define HSZ 512
#define OSZ 256
#define NLAUNCH 64       // all 64 blocks run the XCD election; 8 winners persist
#define RTHREADS 512     // 8 waves; NO intra-block coupling in the main loop
#define KFAST 8          // fast-poll iterations before falling back
#define LATCH_T 48       // fast-path verification window (steps)

typedef unsigned long long u64;
typedef _Float16 half2_t __attribute__((ext_vector_type(2)));

#if defined(__has_builtin)
#if __has_builtin(__builtin_amdgcn_fdot2)
#define HAVE_FDOT2 1
#endif
#endif

__device__ __forceinline__ float dot2f(half2_t a, half2_t b, float c) {
#ifdef HAVE_FDOT2
  return __builtin_amdgcn_fdot2(a, b, c, false);   // v_dot2_f32_f16
#else
  return fmaf((float)a.x, (float)b.x, fmaf((float)a.y, (float)b.y, c));
#endif
}
__device__ __forceinline__ half2_t bch2(unsigned u) {
  return __builtin_bit_cast(half2_t, u);
}
__device__ __forceinline__ unsigned pkrtz_u(float x, float y) {
  return __builtin_bit_cast(unsigned, __builtin_amdgcn_cvt_pkrtz(x, y));
}
__device__ __forceinline__ float u2f(u64 v) {
  return __uint_as_float((unsigned)v);
}

// ---------------------------------------------------------------------------
// Generic tiled GEMM:  C[M,N] = A[M,K] @ W[N,K]^T + bias[N]   (unchanged)
// ---------------------------------------------------------------------------
__global__ __launch_bounds__(256) void gemm_bt_bias(
    const float* __restrict__ A, const float* __restrict__ W,
    const float* __restrict__ bias, float* __restrict__ C,
    int M, int N, int K)
{
  __shared__ float As[32][68];
  __shared__ float Bs[32][68];
  const int tx = threadIdx.x;
  const int tn = tx & 15, tm = tx >> 4;
  const int m0 = blockIdx.x * 64, n0 = blockIdx.y * 64;
  const int kl = tx & 31;
  const int rl = tx >> 5;
  float acc[4][4] = {};

  for (int kt = 0; kt < K; kt += 32) {
#pragma unroll
    for (int i = 0; i < 8; ++i) {
      int m = rl + i * 8;
      As[kl][m] = A[(size_t)(m0 + m) * K + kt + kl];
      Bs[kl][m] = W[(size_t)(n0 + m) * K + kt + kl];
    }
    __syncthreads();
#pragma unroll
    for (int k = 0; k < 32; ++k) {
      float a[4], b[4];
#pragma unroll
      for (int i = 0; i < 4; ++i) a[i] = As[k][tm * 4 + i];
#pragma unroll
      for (int j = 0; j < 4; ++j) b[j] = Bs[k][tn * 4 + j];
#pragma unroll
      for (int i = 0; i < 4; ++i)
#pragma unroll
        for (int j = 0; j < 4; ++j)
          acc[i][j] = fmaf(a[i], b[j], acc[i][j]);
    }
    __syncthreads();
  }
#pragma unroll
  for (int i = 0; i < 4; ++i) {
    int m = m0 + tm * 4 + i;
#pragma unroll
    for (int j = 0; j < 4; ++j) {
      int n = n0 + tn * 4 + j;
      C[(size_t)m * N + n] = acc[i][j] + bias[n];
    }
  }
}

// 8 tagged u64 loads, stride 512 B, one vmcnt drain. sc0 = L1-bypass/L2-scope.
__device__ __forceinline__ void load8_fast(const u64* p,
    u64& a, u64& b, u64& c, u64& d, u64& e, u64& f, u64& g, u64& h) {
  asm volatile(
      "global_load_dwordx2 %0, %8, off sc0\n\t"
      "global_load_dwordx2 %1, %8, off offset:512 sc0\n\t"
      "global_load_dwordx2 %2, %8, off offset:1024 sc0\n\t"
      "global_load_dwordx2 %3, %8, off offset:1536 sc0\n\t"
      "global_load_dwordx2 %4, %8, off offset:2048 sc0\n\t"
      "global_load_dwordx2 %5, %8, off offset:2560 sc0\n\t"
      "global_load_dwordx2 %6, %8, off offset:3072 sc0\n\t"
      "global_load_dwordx2 %7, %8, off offset:3584 sc0\n\t"
      "s_waitcnt vmcnt(0)"
      : "=&v"(a), "=&v"(b), "=&v"(c), "=&v"(d),
        "=&v"(e), "=&v"(f), "=&v"(g), "=&v"(h)
      : "v"(p) : "memory");
}
__device__ __forceinline__ void store_fast(u64* p, u64 v) {
  asm volatile("global_store_dwordx2 %0, %1, off sc0" :: "v"(p), "v"(v)
               : "memory");
}

__device__ __forceinline__ float tanh_c(float s) {
  float xv = fminf(fmaxf(s, -15.f), 15.f);
  float e = __expf(2.f * xv);
  return fmaf(-2.f, __builtin_amdgcn_rcpf(e + 1.f), 1.f);
}

// Poll the 8 tagged partials for one h-chunk; fast ring (sc0) with bounded
// retries, then the agent-scope slow ring (r10-proven fabric path). Returns
// the fixed-order sum (bitwise identical across all redundant consumers).
__device__ __forceinline__ float acquire_sum(const u64* fb, const u64* sb,
                                             unsigned tt, int& use_fast,
                                             int& fastok, int tl) {
  u64 v0 = 0, v1 = 0, v2 = 0, v3 = 0, v4 = 0, v5 = 0, v6 = 0, v7 = 0;
  int got = 0;
  if (use_fast) {
    for (int k = 0; k < KFAST; ++k) {
      load8_fast(fb, v0, v1, v2, v3, v4, v5, v6, v7);
      int ok = ((unsigned)(v0 >> 32) == tt) & ((unsigned)(v1 >> 32) == tt) &
               ((unsigned)(v2 >> 32) == tt) & ((unsigned)(v3 >> 32) == tt) &
               ((unsigned)(v4 >> 32) == tt) & ((unsigned)(v5 >> 32) == tt) &
               ((unsigned)(v6 >> 32) == tt) & ((unsigned)(v7 >> 32) == tt);
      if (__all(ok)) { got = 1; break; }
    }
    if (tl <= LATCH_T) {
      fastok += got;
      if (tl == LATCH_T && fastok < LATCH_T - 8) use_fast = 0;
    }
  }
  if (!got) {
    for (;;) {
      u64 x0 = __hip_atomic_load(sb + 0 * 64, __ATOMIC_RELAXED, __HIP_MEMORY_SCOPE_AGENT);
      u64 x1 = __hip_atomic_load(sb + 1 * 64, __ATOMIC_RELAXED, __HIP_MEMORY_SCOPE_AGENT);
      u64 x2 = __hip_atomic_load(sb + 2 * 64, __ATOMIC_RELAXED, __HIP_MEMORY_SCOPE_AGENT);
      u64 x3 = __hip_atomic_load(sb + 3 * 64, __ATOMIC_RELAXED, __HIP_MEMORY_SCOPE_AGENT);
      u64 x4 = __hip_atomic_load(sb + 4 * 64, __ATOMIC_RELAXED, __HIP_MEMORY_SCOPE_AGENT);
      u64 x5 = __hip_atomic_load(sb + 5 * 64, __ATOMIC_RELAXED, __HIP_MEMORY_SCOPE_AGENT);
      u64 x6 = __hip_atomic_load(sb + 6 * 64, __ATOMIC_RELAXED, __HIP_MEMORY_SCOPE_AGENT);
      u64 x7 = __hip_atomic_load(sb + 7 * 64, __ATOMIC_RELAXED, __HIP_MEMORY_SCOPE_AGENT);
      int ok = ((unsigned)(x0 >> 32) == tt) & ((unsigned)(x1 >> 32) == tt) &
               ((unsigned)(x2 >> 32) == tt) & ((unsigned)(x3 >> 32) == tt) &
               ((unsigned)(x4 >> 32) == tt) & ((unsigned)(x5 >> 32) == tt) &
               ((unsigned)(x6 >> 32) == tt) & ((unsigned)(x7 >> 32) == tt);
      if (__all(ok)) {
        v0 = x0; v1 = x1; v2 = x2; v3 = x3;
        v4 = x4; v5 = x5; v6 = x6; v7 = x7;
        break;
      }
    }
  }
  return ((u2f(v0) + u2f(v1)) + (u2f(v2) + u2f(v3))) +
         ((u2f(v4) + u2f(v5)) + (u2f(v6) + u2f(v7)));
}

// ---------------------------------------------------------------------------
// Persistent recurrence, ROUND-14: partial-exchange, redundant tanh,
// ZERO barriers in the main loop.
//
// r13 post-mortem: election+barrier-reduce bought only -8% -> the home-wave
// aggregator structure itself (detect -> barrier -> LDS reduce -> tanh ->
// publish) serializes ~2175cy/step. This round removes the aggregator:
// wave (w,g) publishes its raw PARTIAL (rows-chunk g x k-chunk w) tagged
// into a single ring copy; every wave reconstructs its needed h-chunk w by
// polling the 8 partials of chunk w (8 parallel loads, one vmcnt) and
// computing sum+clamp+exp+rcp itself (8x redundant; VALU is 1% busy; fixed
// sum tree -> bitwise-identical h everywhere -> no drift). Wave 0 folds
// P[t] into its partial (2-deep HBM prefetch). No __syncthreads, no LDS
// partials, no home wave. Chain/step = publish->L2 visible -> 8-wide
// tagged detect -> sum+tanh+pack -> 32xdot2 -> publish (~800-1000cy).
//
// Fallback: partials dual-published (sc0 fast ring + agent-scope slow ring,
// the r10-proven fabric path), both tagged, 4 slots. Producer at step T
// transitively requires ALL 64 waves to have finished step T-3 (dense
// coupling: (c,g) <- (q,c) for all q reaches every wave in <=3 hops), and
// finishing step T-3 implies having READ tag T-3 -> slot reuse at T is
// safe; slow ring guarantees progress under any placement (G16).
// Diagonal wave (w==g) writes h_hist[t] rows (plain stores; phase-3 launch
// boundary orders them). Sentinel h_hist memsets dropped.
// ---------------------------------------------------------------------------
__global__ __launch_bounds__(RTHREADS, 2) void rnn_recur(
    const float* __restrict__ P,     // [SEQ][HSZ]
    const float* __restrict__ Wh,    // [HSZ][HSZ]
    float* __restrict__ h_hist,      // [SEQ+1][HSZ]; rows 1..SEQ written here
    u64* __restrict__ fring,         // [4 slot][8 chunk][8 qwave][64] tagged
    u64* __restrict__ sring,         // same layout, agent-scope copy
    int* __restrict__ elect)         // [0..7]=per-XCD count, [8]=winner (-1)
{
  const int tid = threadIdx.x;
  const int w = tid >> 6;            // wave 0..7 = k-chunk owner
  const int l = tid & 63;

  __shared__ int s_role;

  // -------- one-time election (tid 0 of every block) --------
  if (tid == 0) {
    unsigned xcc;
    asm volatile("s_getreg_b32 %0, hwreg(HW_REG_XCC_ID)" : "=s"(xcc));
    xcc &= 7u;
    int role = -1;
    int r = __hip_atomic_fetch_add(&elect[xcc], 1, __ATOMIC_RELAXED,
                                   __HIP_MEMORY_SCOPE_AGENT);
    if (r < 8) {
      if (r == 7) {                  // 8th block on this XCD: declare winner
        int exp_ = -1;
        (void)__hip_atomic_compare_exchange_strong(
            &elect[8], &exp_, (int)xcc,
            __ATOMIC_RELEASE, __ATOMIC_RELAXED, __HIP_MEMORY_SCOPE_AGENT);
      }
      int wv;
      do {
        wv = __hip_atomic_load(&elect[8], __ATOMIC_ACQUIRE,
                               __HIP_MEMORY_SCOPE_AGENT);
      } while (wv < 0);              // guaranteed: pigeonhole 64 blocks / 8 XCDs
      if (wv == (int)xcc) role = r;  // ranks 0..7 on winner XCD participate
    }
    s_role = role;
  }
  __syncthreads();                   // prologue only
  const int g = s_role;              // participant id 0..7, or -1
  if (g < 0) return;

  const int g64 = g << 6;
  const int row = g64 + l;           // block owns output rows [g64, g64+64)
  const int kbase = w << 6;          // wave owns k-chunk w

  // Lane's 64 weights, f16-packed: 32 half2 regs (r10-proven dot).
  unsigned wreg[32];
  {
    const float2* ws = (const float2*)(Wh + (size_t)row * HSZ + kbase);
#pragma unroll
    for (int j = 0; j < 32; ++j) {
      float2 f = ws[j];
      unsigned u = pkrtz_u(f.x, f.y);
      asm("" : "+v"(u));
      wreg[j] = u;
    }
  }

  // 2-deep P prefetch (wave 0 folds P into its partial).
  float pv = 0.f, pv1 = 0.f;
  if (w == 0) {
    pv  = P[row];
    pv1 = P[HSZ + row];
  }
  int use_fast = 1, fastok = 0;

  for (int t = 0; t < SEQ; ++t) {
    float pv2 = 0.f;
    if (w == 0) {                    // prefetch P[t+2]; used in 2 steps
      int ti = t + 2 < SEQ ? t + 2 : SEQ - 1;
      pv2 = P[(size_t)ti * HSZ + row];
    }

    // ---- acquire h[t]-chunk w (reconstruct from 8 partials) ----
    float vh = 0.f;
    if (t > 0) {
      const size_t ci = (((size_t)(t & 3) * 8 + w) * 8) * 64 + l;
      float s8 = acquire_sum(fring + ci, sring + ci, (unsigned)t,
                             use_fast, fastok, t);
      vh = tanh_c(s8);
      if (w == g)                    // diagonal wave materializes h_hist[t]
        h_hist[(size_t)t * HSZ + row] = vh;
    }

    // ---- dot: partial for rows-chunk g over k-chunk w ----
    float vn = __shfl_xor(vh, 1);
    unsigned hpu = pkrtz_u(vh, vn);
    float a0 = 0.f, a1 = 0.f, a2 = 0.f, a3 = 0.f;
#pragma unroll
    for (int j = 0; j < 8; ++j) {
      a0 = dot2f(bch2(wreg[4 * j + 0]),
                 bch2(__builtin_amdgcn_readlane(hpu, 8 * j + 0)), a0);
      a1 = dot2f(bch2(wreg[4 * j + 1]),
                 bch2(__builtin_amdgcn_readlane(hpu, 8 * j + 2)), a1);
      a2 = dot2f(bch2(wreg[4 * j + 2]),
                 bch2(__builtin_amdgcn_readlane(hpu, 8 * j + 4)), a2);
      a3 = dot2f(bch2(wreg[4 * j + 3]),
                 bch2(__builtin_amdgcn_readlane(hpu, 8 * j + 6)), a3);
    }
    float part = (a0 + a1) + (a2 + a3);
    if (w == 0) {                    // fold P[t]; rotate prefetch pipe
      part += pv;
      pv = pv1;
      pv1 = pv2;
    }

    // ---- dual publish: tagged {t+1, partial} ----
    const u64 pk = ((u64)(unsigned)(t + 1) << 32) | (u64)__float_as_uint(part);
    const size_t oi = (((size_t)((t + 1) & 3) * 8 + g) * 8 + w) * 64 + l;
    store_fast(fring + oi, pk);
    __hip_atomic_store(sring + oi, pk, __ATOMIC_RELAXED,
                       __HIP_MEMORY_SCOPE_AGENT);
  }

  // Epilogue: h[SEQ] is consumed by nobody in-loop; diagonal wave
  // reconstructs it once and completes h_hist for phase 3.
  if (w == g) {
    const size_t ci = (((size_t)(SEQ & 3) * 8 + w) * 8) * 64 + l;
    float s8 = acquire_sum(fring + ci, sring + ci, (unsigned)SEQ,
                           use_fast, fastok, SEQ);
    h_hist[(size_t)SEQ * HSZ + row] = tanh_c(s8);
  }
}

// ---------------------------------------------------------------------------
extern "C" void kernel_launch(void* const* d_in, const int* in_sizes, int n_in,
                              void* d_out, int out_size, void* d_ws, size_t ws_size,
                              hipStream_t stream) {
  const float* x  = (const float*)d_in[0];  // [SEQ][ISZ]
  const float* Wx = (const float*)d_in[1];  // [HSZ][ISZ]
  const float* Wh = (const float*)d_in[2];  // [HSZ][HSZ]
  const float* Wy = (const float*)d_in[3];  // [OSZ][HSZ]
  const float* bh = (const float*)d_in[4];  // [HSZ]
  const float* by = (const float*)d_in[5];  // [OSZ]
  float* out = (float*)d_out;               // [SEQ][OSZ]

  float* P      = (float*)d_ws;                             // 64 MB
  float* h_hist = P + (size_t)SEQ * HSZ;                    // 64 MB + 2 KB
  u64*   fring  = (u64*)(h_hist + (size_t)(SEQ + 1) * HSZ); // 128 KB
  u64*   sring  = fring + (size_t)4 * 8 * 8 * 64;           // 128 KB
  int*   elect  = (int*)(sring + (size_t)4 * 8 * 8 * 64);   // 9 ints

  // Zero ring tags (expected tags start at 1); reset election state.
  (void)hipMemsetAsync(fring, 0, (size_t)4 * 8 * 8 * 64 * sizeof(u64), stream);
  (void)hipMemsetAsync(sring, 0, (size_t)4 * 8 * 8 * 64 * sizeof(u64), stream);
  (void)hipMemsetAsync(elect, 0, 8 * sizeof(int), stream);
  (void)hipMemsetAsync(elect + 8, 0xFF, sizeof(int), stream); // winner = -1

  // Phase 1: P = x @ Wx^T + bh
  gemm_bt_bias<<<dim3(SEQ / 64, HSZ / 64), dim3(256), 0, stream>>>(
      x, Wx, bh, P, SEQ, HSZ, ISZ);

  // Phase 2: recurrence (8 participants, elected same-XCD at runtime)
  rnn_recur<<<dim3(NLAUNCH), dim3(RTHREADS), 0, stream>>>(
      P, Wh, h_hist, fring, sring, elect);

  // Phase 3: y = h_hist[1..] @ Wy^T + by
  gemm_bt_bias<<<dim3(SEQ / 64, OSZ / 64), dim3(256), 0, stream>>>(
      h_hist + HSZ, Wy, by, out, SEQ, OSZ, HSZ);
}

// Round 3
// 36195.261 us; speedup vs baseline: 1.3428x; 1.3428x over previous
//
#include <hip/hip_runtime.h>

#define SEQ 32768
#define ISZ 256
#define HSZ 512
#define OSZ 256
#define NLAUNCH 64       // all 64 blocks run the XCD election; 8 winners persist
#define RTHREADS 512     // 8 waves: wave g is "home" (reduce+publish), rest poll
#define SENT 0x7FAAAAAAu // NaN sentinel for the slow (fabric) path
#define KFAST 8          // fast-poll iterations before falling back
#define LATCH_T 48       // fast-path verification window (steps)

typedef unsigned long long u64;
typedef _Float16 half2_t __attribute__((ext_vector_type(2)));

#if defined(__has_builtin)
#if __has_builtin(__builtin_amdgcn_fdot2)
#define HAVE_FDOT2 1
#endif
#endif

__device__ __forceinline__ float dot2f(half2_t a, half2_t b, float c) {
#ifdef HAVE_FDOT2
  return __builtin_amdgcn_fdot2(a, b, c, false);   // v_dot2_f32_f16
#else
  return fmaf((float)a.x, (float)b.x, fmaf((float)a.y, (float)b.y, c));
#endif
}
__device__ __forceinline__ half2_t bch2(unsigned u) {
  return __builtin_bit_cast(half2_t, u);
}
__device__ __forceinline__ unsigned pkrtz_u(float x, float y) {
  return __builtin_bit_cast(unsigned, __builtin_amdgcn_cvt_pkrtz(x, y));
}

// ---------------------------------------------------------------------------
// Generic tiled GEMM:  C[M,N] = A[M,K] @ W[N,K]^T + bias[N]   (unchanged)
// ---------------------------------------------------------------------------
__global__ __launch_bounds__(256) void gemm_bt_bias(
    const float* __restrict__ A, const float* __restrict__ W,
    const float* __restrict__ bias, float* __restrict__ C,
    int M, int N, int K)
{
  __shared__ float As[32][68];
  __shared__ float Bs[32][68];
  const int tx = threadIdx.x;
  const int tn = tx & 15, tm = tx >> 4;
  const int m0 = blockIdx.x * 64, n0 = blockIdx.y * 64;
  const int kl = tx & 31;
  const int rl = tx >> 5;
  float acc[4][4] = {};

  for (int kt = 0; kt < K; kt += 32) {
#pragma unroll
    for (int i = 0; i < 8; ++i) {
      int m = rl + i * 8;
      As[kl][m] = A[(size_t)(m0 + m) * K + kt + kl];
      Bs[kl][m] = W[(size_t)(n0 + m) * K + kt + kl];
    }
    __syncthreads();
#pragma unroll
    for (int k = 0; k < 32; ++k) {
      float a[4], b[4];
#pragma unroll
      for (int i = 0; i < 4; ++i) a[i] = As[k][tm * 4 + i];
#pragma unroll
      for (int j = 0; j < 4; ++j) b[j] = Bs[k][tn * 4 + j];
#pragma unroll
      for (int i = 0; i < 4; ++i)
#pragma unroll
        for (int j = 0; j < 4; ++j)
          acc[i][j] = fmaf(a[i], b[j], acc[i][j]);
    }
    __syncthreads();
  }
#pragma unroll
  for (int i = 0; i < 4; ++i) {
    int m = m0 + tm * 4 + i;
#pragma unroll
    for (int j = 0; j < 4; ++j) {
      int n = n0 + tn * 4 + j;
      C[(size_t)m * N + n] = acc[i][j] + bias[n];
    }
  }
}

// Slow path (r10-proven): 2-deep pipelined sentinel poll, fabric-coherent.
__device__ __forceinline__ float poll_sent(const float* p, unsigned sent) {
  float a, b;
  asm volatile(
      "s_waitcnt vmcnt(0)\n\t"
      "global_load_dword %0, %2, off sc0 sc1\n\t"
      "global_load_dword %1, %2, off sc0 sc1\n"
      "1:\n\t"
      "s_waitcnt vmcnt(1)\n\t"
      "v_cmp_eq_u32 vcc, %3, %0\n\t"
      "s_cbranch_vccz 3f\n\t"
      "global_load_dword %0, %2, off sc0 sc1\n\t"
      "s_waitcnt vmcnt(1)\n\t"
      "v_cmp_eq_u32 vcc, %3, %1\n\t"
      "s_cbranch_vccz 2f\n\t"
      "global_load_dword %1, %2, off sc0 sc1\n\t"
      "s_branch 1b\n"
      "2:\n\t"
      "v_mov_b32 %0, %1\n"
      "3:\n\t"
      "s_waitcnt vmcnt(0)"
      : "=&v"(a), "=&v"(b)
      : "v"(p), "v"(sent)
      : "memory", "vcc");
  return a;
}

// Fast-path consumer load: sc0 (L1-bypass, reads L2). The ring is written by
// device-scope atomics, which execute AT the L2 -- so an sc0 load observes
// them as soon as they land. Bounded retries + sentinel fallback keep
// correctness placement-independent.
__device__ __forceinline__ u64 load_fast(const u64* p) {
  u64 v;
  asm volatile("global_load_dwordx2 %0, %1, off sc0\n\t"
               "s_waitcnt vmcnt(0)"
               : "=v"(v) : "v"(p) : "memory");
  return v;
}

// ---------------------------------------------------------------------------
// Persistent recurrence, ROUND-15: r13 structure + ATOMIC publish.
//
// r14 post-mortem: partial-exchange + agent-scope slow ring regressed to
// 48.6ms (WRITE_SIZE 1.1GB = sring write-through; FETCH 651MB = latched
// waves polling at HBM latency). Reverted to r13 (29.3ms known-good).
//
// r13 decomposition: local work ~760cy of the 2170cy step -> ~1400cy is
// sc0-store -> remote-CU-load VISIBILITY (the store sits in the CU write
// path before the L2 line is serveable). Fix: publish the fan-out ring via
// fire-and-forget atomicExch (global_atomic_swap_x2) -- atomics execute AT
// the L2 atomic unit, making the value serveable immediately, and are
// fabric-coherent (strengthens the fallback). Riders: part[2][64][8] so
// home reduces with 2x ds_read_b128 (not 8 serial b32); s_setprio(1)
// around home's post-barrier serial segment.
// ---------------------------------------------------------------------------
__global__ __launch_bounds__(RTHREADS, 2) void rnn_recur(
    const float* __restrict__ P,     // [SEQ][HSZ]
    const float* __restrict__ Wh,    // [HSZ][HSZ]
    float* __restrict__ h_hist,      // [SEQ+1][HSZ]; row0=0, rows 1..=SENT
    u64* __restrict__ fring,         // [8 consumerWG][4 slot][8 chunk][64]
    int* __restrict__ elect)         // [0..7]=per-XCD count, [8]=winner (-1)
{
  const int tid = threadIdx.x;
  const int w = tid >> 6;            // wave 0..7
  const int l = tid & 63;

  __shared__ float part[2][64][8];   // [buf][lane][wave] -> home reads b128x2
  __shared__ int s_role;

  // -------- one-time election (tid 0 of every block) --------
  if (tid == 0) {
    unsigned xcc;
    asm volatile("s_getreg_b32 %0, hwreg(HW_REG_XCC_ID)" : "=s"(xcc));
    xcc &= 7u;
    int role = -1;
    int r = __hip_atomic_fetch_add(&elect[xcc], 1, __ATOMIC_RELAXED,
                                   __HIP_MEMORY_SCOPE_AGENT);
    if (r < 8) {
      if (r == 7) {                  // 8th block on this XCD: declare winner
        int exp_ = -1;
        (void)__hip_atomic_compare_exchange_strong(
            &elect[8], &exp_, (int)xcc,
            __ATOMIC_RELEASE, __ATOMIC_RELAXED, __HIP_MEMORY_SCOPE_AGENT);
      }
      int wv;
      do {
        wv = __hip_atomic_load(&elect[8], __ATOMIC_ACQUIRE,
                               __HIP_MEMORY_SCOPE_AGENT);
      } while (wv < 0);              // guaranteed: pigeonhole 64 blocks / 8 XCDs
      if (wv == (int)xcc) role = r;  // ranks 0..7 on winner XCD participate
    }
    s_role = role;
  }
  __syncthreads();
  const int g = s_role;              // participant id 0..7, or -1
  if (g < 0) return;

  const int g64 = g << 6;
  const int row = g64 + l;           // block owns output rows [g64, g64+64)
  const int kbase = w << 6;          // wave owns k-chunk w

  // Lane's 64 weights, f16-packed: 32 half2 regs (r10-proven dot).
  unsigned wreg[32];
  {
    const float2* ws = (const float2*)(Wh + (size_t)row * HSZ + kbase);
#pragma unroll
    for (int j = 0; j < 32; ++j) {
      float2 f = ws[j];
      unsigned u = pkrtz_u(f.x, f.y);
      asm("" : "+v"(u));
      wreg[j] = u;
    }
  }

  const bool home = (w == g);        // home wave: chunk g lives in hreg
  float hreg = 0.f;                  // h[t][row] for home wave (h[0]=0)
  float pv = home ? P[row] : 0.f;    // P[t], prefetched one step ahead
  float pvn = 0.f;
  int fastok = 0, use_fast = 1;

  for (int t = 0; t < SEQ; ++t) {
    float vh = 0.f;
    if (home) {
      vh = hreg;                     // register-local, zero-latency
    } else if (t > 0) {
      int got = 0;
      if (use_fast) {
        const u64* fp = fring + (((size_t)g * 4 + (t & 3)) * 8 + w) * 64 + l;
        for (int k = 0; k < KFAST; ++k) {
          u64 v = load_fast(fp);
          if (__all((int)((unsigned)(v >> 32) == (unsigned)t))) {
            vh = __uint_as_float((unsigned)v);
            got = 1;
            break;
          }
        }
        if (t <= LATCH_T) {
          fastok += got;
          if (t == LATCH_T && fastok < LATCH_T - 8) use_fast = 0;
        }
      }
      if (!got)
        vh = poll_sent(h_hist + (size_t)t * HSZ + kbase + l, SENT);
    }

    // Pack h to f16 pairs; 32 readlane + 32 dot2, 4 accumulator chains.
    float vn = __shfl_xor(vh, 1);
    unsigned hpu = pkrtz_u(vh, vn);
    float a0 = 0.f, a1 = 0.f, a2 = 0.f, a3 = 0.f;
#pragma unroll
    for (int j = 0; j < 8; ++j) {
      a0 = dot2f(bch2(wreg[4 * j + 0]),
                 bch2(__builtin_amdgcn_readlane(hpu, 8 * j + 0)), a0);
      a1 = dot2f(bch2(wreg[4 * j + 1]),
                 bch2(__builtin_amdgcn_readlane(hpu, 8 * j + 2)), a1);
      a2 = dot2f(bch2(wreg[4 * j + 2]),
                 bch2(__builtin_amdgcn_readlane(hpu, 8 * j + 4)), a2);
      a3 = dot2f(bch2(wreg[4 * j + 3]),
                 bch2(__builtin_amdgcn_readlane(hpu, 8 * j + 6)), a3);
    }
    part[t & 1][l][w] = (a0 + a1) + (a2 + a3);

    __syncthreads();                 // ONE barrier/step (part double-buffered)

    if (home) {
      __builtin_amdgcn_s_setprio(1); // serial segment: favor this wave
      // P prefetch for t+1: issued now, consumed next step.
      pvn = P[(size_t)(t + 1 < SEQ ? t + 1 : SEQ - 1) * HSZ + row];
      const int buf = t & 1;
      const float4* pp = (const float4*)&part[buf][l][0];
      float4 A = pp[0];              // ds_read_b128: partials of waves 0..3
      float4 B = pp[1];              // ds_read_b128: partials of waves 4..7
      float s = ((A.x + A.y) + (A.z + A.w)) + ((B.x + B.y) + (B.z + B.w));
      float xv = s + pv;
      xv = fminf(fmaxf(xv, -15.f), 15.f);
      float e = __expf(2.f * xv);
      float hn = fmaf(-2.f, __builtin_amdgcn_rcpf(e + 1.f), 1.f); // tanh(xv)
      hreg = hn;
      // ATOMIC publish: swap executes at the L2 atomic unit -> immediately
      // serveable to remote CUs' sc0 polls (and fabric-coherent).
      const u64 pk = ((u64)(unsigned)(t + 1) << 32) | (u64)__float_as_uint(hn);
      const int slot = (t + 1) & 3;
#pragma unroll
      for (int j = 0; j < 8; ++j)
        (void)atomicExch(
            (u64*)(fring + (((size_t)j * 4 + slot) * 8 + g) * 64 + l), pk);
      // Slow-path + final-output publish (fabric; value IS the signal).
      __hip_atomic_store(&h_hist[(size_t)(t + 1) * HSZ + row], hn,
                         __ATOMIC_RELAXED, __HIP_MEMORY_SCOPE_AGENT);
      pv = pvn;
      __builtin_amdgcn_s_setprio(0);
    }
  }
}

// ---------------------------------------------------------------------------
extern "C" void kernel_launch(void* const* d_in, const int* in_sizes, int n_in,
                              void* d_out, int out_size, void* d_ws, size_t ws_size,
                              hipStream_t stream) {
  const float* x  = (const float*)d_in[0];  // [SEQ][ISZ]
  const float* Wx = (const float*)d_in[1];  // [HSZ][ISZ]
  const float* Wh = (const float*)d_in[2];  // [HSZ][HSZ]
  const float* Wy = (const float*)d_in[3];  // [OSZ][HSZ]
  const float* bh = (const float*)d_in[4];  // [HSZ]
  const float* by = (const float*)d_in[5];  // [OSZ]
  float* out = (float*)d_out;               // [SEQ][OSZ]

  float* P      = (float*)d_ws;             // SEQ*HSZ      (64 MB)
  float* h_hist = P + (size_t)SEQ * HSZ;    // (SEQ+1)*HSZ  (64 MB)
  u64*   fring  = (u64*)(h_hist + (size_t)(SEQ + 1) * HSZ); // 128 KB
  int*   elect  = (int*)(fring + (size_t)8 * 4 * 8 * 64);   // 9 ints

  // Sentinel-fill h_hist (slow path), zero row 0; zero fring tags; reset
  // election state (counts=0, winner=-1) every replay.
  (void)hipMemsetD32Async((hipDeviceptr_t)h_hist, (int)SENT,
                          (size_t)(SEQ + 1) * HSZ, stream);
  (void)hipMemsetAsync(h_hist, 0, HSZ * sizeof(float), stream);
  (void)hipMemsetAsync(fring, 0, (size_t)8 * 4 * 8 * 64 * sizeof(u64), stream);
  (void)hipMemsetAsync(elect, 0, 8 * sizeof(int), stream);
  (void)hipMemsetAsync(elect + 8, 0xFF, sizeof(int), stream); // winner = -1

  // Phase 1: P = x @ Wx^T + bh
  gemm_bt_bias<<<dim3(SEQ / 64, HSZ / 64), dim3(256), 0, stream>>>(
      x, Wx, bh, P, SEQ, HSZ, ISZ);

  // Phase 2: recurrence (8 participants, elected same-XCD at runtime)
  rnn_recur<<<dim3(NLAUNCH), dim3(RTHREADS), 0, stream>>>(
      P, Wh, h_hist, fring, elect);

  // Phase 3: y = h_hist[1..] @ Wy^T + by
  gemm_bt_bias<<<dim3(SEQ / 64, OSZ / 64), dim3(256), 0, stream>>>(
      h_hist + HSZ, Wy, by, out, SEQ, OSZ, HSZ);
}

// Round 4
// 30202.505 us; speedup vs baseline: 1.6093x; 1.1984x over previous
//
#include <hip/hip_runtime.h>

#define SEQ 32768
#define ISZ 256
#define HSZ 512
#define OSZ 256
#define NLAUNCH 128      // 16 blocks/XCD: warmers present on the winner XCD too
#define RTHREADS 512     // 8 waves: wave g is "home" (reduce+publish), rest poll
#define SENT 0x7FAAAAAAu // NaN sentinel for the slow (fabric) path
#define KFAST 8          // fast-poll iterations before falling back
#define LATCH_T 48       // fast-path verification window (steps)
#define WARM_CAP (1 << 20) // warmer iteration cap (~56ms @2.4GHz) - safety net

typedef unsigned long long u64;
typedef _Float16 half2_t __attribute__((ext_vector_type(2)));

#if defined(__has_builtin)
#if __has_builtin(__builtin_amdgcn_fdot2)
#define HAVE_FDOT2 1
#endif
#endif

__device__ __forceinline__ float dot2f(half2_t a, half2_t b, float c) {
#ifdef HAVE_FDOT2
  return __builtin_amdgcn_fdot2(a, b, c, false);   // v_dot2_f32_f16
#else
  return fmaf((float)a.x, (float)b.x, fmaf((float)a.y, (float)b.y, c));
#endif
}
__device__ __forceinline__ half2_t bch2(unsigned u) {
  return __builtin_bit_cast(half2_t, u);
}
__device__ __forceinline__ unsigned pkrtz_u(float x, float y) {
  return __builtin_bit_cast(unsigned, __builtin_amdgcn_cvt_pkrtz(x, y));
}

// ---------------------------------------------------------------------------
// Generic tiled GEMM:  C[M,N] = A[M,K] @ W[N,K]^T + bias[N]   (unchanged)
// ---------------------------------------------------------------------------
__global__ __launch_bounds__(256) void gemm_bt_bias(
    const float* __restrict__ A, const float* __restrict__ W,
    const float* __restrict__ bias, float* __restrict__ C,
    int M, int N, int K)
{
  __shared__ float As[32][68];
  __shared__ float Bs[32][68];
  const int tx = threadIdx.x;
  const int tn = tx & 15, tm = tx >> 4;
  const int m0 = blockIdx.x * 64, n0 = blockIdx.y * 64;
  const int kl = tx & 31;
  const int rl = tx >> 5;
  float acc[4][4] = {};

  for (int kt = 0; kt < K; kt += 32) {
#pragma unroll
    for (int i = 0; i < 8; ++i) {
      int m = rl + i * 8;
      As[kl][m] = A[(size_t)(m0 + m) * K + kt + kl];
      Bs[kl][m] = W[(size_t)(n0 + m) * K + kt + kl];
    }
    __syncthreads();
#pragma unroll
    for (int k = 0; k < 32; ++k) {
      float a[4], b[4];
#pragma unroll
      for (int i = 0; i < 4; ++i) a[i] = As[k][tm * 4 + i];
#pragma unroll
      for (int j = 0; j < 4; ++j) b[j] = Bs[k][tn * 4 + j];
#pragma unroll
      for (int i = 0; i < 4; ++i)
#pragma unroll
        for (int j = 0; j < 4; ++j)
          acc[i][j] = fmaf(a[i], b[j], acc[i][j]);
    }
    __syncthreads();
  }
#pragma unroll
  for (int i = 0; i < 4; ++i) {
    int m = m0 + tm * 4 + i;
#pragma unroll
    for (int j = 0; j < 4; ++j) {
      int n = n0 + tn * 4 + j;
      C[(size_t)m * N + n] = acc[i][j] + bias[n];
    }
  }
}

// Slow path (r10-proven): 2-deep pipelined sentinel poll, fabric-coherent.
__device__ __forceinline__ float poll_sent(const float* p, unsigned sent) {
  float a, b;
  asm volatile(
      "s_waitcnt vmcnt(0)\n\t"
      "global_load_dword %0, %2, off sc0 sc1\n\t"
      "global_load_dword %1, %2, off sc0 sc1\n"
      "1:\n\t"
      "s_waitcnt vmcnt(1)\n\t"
      "v_cmp_eq_u32 vcc, %3, %0\n\t"
      "s_cbranch_vccz 3f\n\t"
      "global_load_dword %0, %2, off sc0 sc1\n\t"
      "s_waitcnt vmcnt(1)\n\t"
      "v_cmp_eq_u32 vcc, %3, %1\n\t"
      "s_cbranch_vccz 2f\n\t"
      "global_load_dword %1, %2, off sc0 sc1\n\t"
      "s_branch 1b\n"
      "2:\n\t"
      "v_mov_b32 %0, %1\n"
      "3:\n\t"
      "s_waitcnt vmcnt(0)"
      : "=&v"(a), "=&v"(b)
      : "v"(p), "v"(sent)
      : "memory", "vcc");
  return a;
}

// Fast path: sc0-only (L1-bypass, L2-scope). With the runtime election all
// participants are provably on one XCD. Bounded K + sentinel fallback keeps
// correctness placement-independent.
__device__ __forceinline__ u64 load_fast(const u64* p) {
  u64 v;
  asm volatile("global_load_dwordx2 %0, %1, off sc0\n\t"
               "s_waitcnt vmcnt(0)"
               : "=v"(v) : "v"(p) : "memory");
  return v;
}
__device__ __forceinline__ void store_fast(u64* p, u64 v) {
  asm volatile("global_store_dwordx2 %0, %1, off sc0" :: "v"(p), "v"(v)
               : "memory");
}

// ---------------------------------------------------------------------------
// Persistent recurrence, ROUND-16: r13 structure + CLOCK-WARMER losers.
//
// r15 post-mortem: atomicExch publish writes through to HBM (WRITE_SIZE
// 65MB->1.11GB) and part[64][8] is a 16-way LDS bank conflict (3.1e7) ->
// both reverted; r13 (29.3ms) restored.
//
// New theory: the r13 cycle model sums to ~900cy/step but measures 2175cy
// at NOMINAL clock. VALUBusy 1%, occupancy 0.8%, HBM 0.07% -> the chip
// looks idle to the power governor; if GFX clock sits at ~1-1.2GHz the
// model matches measurement exactly. Fix: losers (120 of 128 blocks,
// including 8 on the winner XCD) spin register-only FMAs, polling a done
// flag every 128 iters (~5us) with a hard 2^20-iter cap (~56ms @2.4GHz) so
// termination never depends on the flag. Warmers touch nothing but the
// flag line: placement-independent, correctness-neutral (G16).
// ---------------------------------------------------------------------------
__global__ __launch_bounds__(RTHREADS, 2) void rnn_recur(
    const float* __restrict__ P,     // [SEQ][HSZ]
    const float* __restrict__ Wh,    // [HSZ][HSZ]
    float* __restrict__ h_hist,      // [SEQ+1][HSZ]; row0=0, rows 1..=SENT
    u64* __restrict__ fring,         // [8 consumerWG][4 slot][8 chunk][64]
    int* __restrict__ elect)         // [0..7]=XCD count, [8]=winner, [9]=done
{
  const int tid = threadIdx.x;
  const int w = tid >> 6;            // wave 0..7
  const int l = tid & 63;

  __shared__ float part[2][8][64];   // [buf][wave][lane] - conflict-free
  __shared__ int s_role;

  // -------- one-time election (tid 0 of every block) --------
  if (tid == 0) {
    unsigned xcc;
    asm volatile("s_getreg_b32 %0, hwreg(HW_REG_XCC_ID)" : "=s"(xcc));
    xcc &= 7u;
    int role = -1;
    int r = __hip_atomic_fetch_add(&elect[xcc], 1, __ATOMIC_RELAXED,
                                   __HIP_MEMORY_SCOPE_AGENT);
    if (r < 8) {
      if (r == 7) {                  // 8th block on this XCD: declare winner
        int exp_ = -1;
        (void)__hip_atomic_compare_exchange_strong(
            &elect[8], &exp_, (int)xcc,
            __ATOMIC_RELEASE, __ATOMIC_RELAXED, __HIP_MEMORY_SCOPE_AGENT);
      }
      int wv;
      do {
        wv = __hip_atomic_load(&elect[8], __ATOMIC_ACQUIRE,
                               __HIP_MEMORY_SCOPE_AGENT);
      } while (wv < 0);              // guaranteed: pigeonhole 128 blocks / 8 XCDs
      if (wv == (int)xcc) role = r;  // ranks 0..7 on winner XCD participate
    }
    s_role = role;
  }
  __syncthreads();
  const int g = s_role;              // participant id 0..7, or -1
  if (g < 0) {
    // ---------------- clock warmer: keep the GFX domain boosted ----------
    float acc = (float)tid * 1.000001f;
    for (int i = 0; i < WARM_CAP; ++i) {
#pragma unroll
      for (int j = 0; j < 32; ++j) acc = fmaf(acc, 1.0000001f, 1e-7f);
      if ((i & 127) == 0) {
        if (__hip_atomic_load(&elect[9], __ATOMIC_RELAXED,
                              __HIP_MEMORY_SCOPE_AGENT))
          break;
      }
    }
    asm volatile("" :: "v"(acc));    // keep the spin live
    return;
  }

  const int g64 = g << 6;
  const int row = g64 + l;           // block owns output rows [g64, g64+64)
  const int kbase = w << 6;          // wave owns k-chunk w

  // Lane's 64 weights, f16-packed: 32 half2 regs (r10-proven dot).
  unsigned wreg[32];
  {
    const float2* ws = (const float2*)(Wh + (size_t)row * HSZ + kbase);
#pragma unroll
    for (int j = 0; j < 32; ++j) {
      float2 f = ws[j];
      unsigned u = pkrtz_u(f.x, f.y);
      asm("" : "+v"(u));
      wreg[j] = u;
    }
  }

  const bool home = (w == g);        // home wave: chunk g lives in hreg
  float hreg = 0.f;                  // h[t][row] for home wave (h[0]=0)
  float pv = home ? P[row] : 0.f;    // P[t], prefetched one step ahead
  float pvn = 0.f;
  int fastok = 0, use_fast = 1;

  for (int t = 0; t < SEQ; ++t) {
    float vh = 0.f;
    if (home) {
      vh = hreg;                     // register-local, zero-latency
    } else if (t > 0) {
      int got = 0;
      if (use_fast) {
        const u64* fp = fring + (((size_t)g * 4 + (t & 3)) * 8 + w) * 64 + l;
        for (int k = 0; k < KFAST; ++k) {
          u64 v = load_fast(fp);
          if (__all((int)((unsigned)(v >> 32) == (unsigned)t))) {
            vh = __uint_as_float((unsigned)v);
            got = 1;
            break;
          }
        }
        if (t <= LATCH_T) {
          fastok += got;
          if (t == LATCH_T && fastok < LATCH_T - 8) use_fast = 0;
        }
      }
      if (!got)
        vh = poll_sent(h_hist + (size_t)t * HSZ + kbase + l, SENT);
    }

    // Pack h to f16 pairs; 32 readlane + 32 dot2, 4 accumulator chains.
    float vn = __shfl_xor(vh, 1);
    unsigned hpu = pkrtz_u(vh, vn);
    float a0 = 0.f, a1 = 0.f, a2 = 0.f, a3 = 0.f;
#pragma unroll
    for (int j = 0; j < 8; ++j) {
      a0 = dot2f(bch2(wreg[4 * j + 0]),
                 bch2(__builtin_amdgcn_readlane(hpu, 8 * j + 0)), a0);
      a1 = dot2f(bch2(wreg[4 * j + 1]),
                 bch2(__builtin_amdgcn_readlane(hpu, 8 * j + 2)), a1);
      a2 = dot2f(bch2(wreg[4 * j + 2]),
                 bch2(__builtin_amdgcn_readlane(hpu, 8 * j + 4)), a2);
      a3 = dot2f(bch2(wreg[4 * j + 3]),
                 bch2(__builtin_amdgcn_readlane(hpu, 8 * j + 6)), a3);
    }
    part[t & 1][w][l] = (a0 + a1) + (a2 + a3);

    __syncthreads();                 // ONE barrier/step (part double-buffered)

    if (home) {
      __builtin_amdgcn_s_setprio(1); // serial segment: favor this wave
      // P prefetch for t+1: issued now, consumed next step.
      pvn = P[(size_t)(t + 1 < SEQ ? t + 1 : SEQ - 1) * HSZ + row];
      const int buf = t & 1;
      float p0 = part[buf][0][l], p1 = part[buf][1][l];
      float p2 = part[buf][2][l], p3 = part[buf][3][l];
      float p4 = part[buf][4][l], p5 = part[buf][5][l];
      float p6 = part[buf][6][l], p7 = part[buf][7][l];
      float s = ((p0 + p1) + (p2 + p3)) + ((p4 + p5) + (p6 + p7));
      float xv = s + pv;
      xv = fminf(fmaxf(xv, -15.f), 15.f);
      float e = __expf(2.f * xv);
      float hn = fmaf(-2.f, __builtin_amdgcn_rcpf(e + 1.f), 1.f); // tanh(xv)
      hreg = hn;
      // Fast publish FIRST (consumer-visible path), tagged {step,val}.
      const u64 pk = ((u64)(unsigned)(t + 1) << 32) | (u64)__float_as_uint(hn);
      const int slot = (t + 1) & 3;
#pragma unroll
      for (int j = 0; j < 8; ++j)
        store_fast(fring + (((size_t)j * 4 + slot) * 8 + g) * 64 + l, pk);
      // Slow-path + final-output publish (fabric; value IS the signal).
      __hip_atomic_store(&h_hist[(size_t)(t + 1) * HSZ + row], hn,
                         __ATOMIC_RELAXED, __HIP_MEMORY_SCOPE_AGENT);
      pv = pvn;
      __builtin_amdgcn_s_setprio(0);
    }
  }

  // Recurrence done: release the warmers.
  if (g == 0 && tid == 0)
    __hip_atomic_store(&elect[9], 1, __ATOMIC_RELAXED,
                       __HIP_MEMORY_SCOPE_AGENT);
}

// ---------------------------------------------------------------------------
extern "C" void kernel_launch(void* const* d_in, const int* in_sizes, int n_in,
                              void* d_out, int out_size, void* d_ws, size_t ws_size,
                              hipStream_t stream) {
  const float* x  = (const float*)d_in[0];  // [SEQ][ISZ]
  const float* Wx = (const float*)d_in[1];  // [HSZ][ISZ]
  const float* Wh = (const float*)d_in[2];  // [HSZ][HSZ]
  const float* Wy = (const float*)d_in[3];  // [OSZ][HSZ]
  const float* bh = (const float*)d_in[4];  // [HSZ]
  const float* by = (const float*)d_in[5];  // [OSZ]
  float* out = (float*)d_out;               // [SEQ][OSZ]

  float* P      = (float*)d_ws;             // SEQ*HSZ      (64 MB)
  float* h_hist = P + (size_t)SEQ * HSZ;    // (SEQ+1)*HSZ  (64 MB)
  u64*   fring  = (u64*)(h_hist + (size_t)(SEQ + 1) * HSZ); // 128 KB
  int*   elect  = (int*)(fring + (size_t)8 * 4 * 8 * 64);   // 10 ints

  // Sentinel-fill h_hist (slow path), zero row 0; zero fring tags; reset
  // election state (counts=0, winner=-1, done=0) every replay.
  (void)hipMemsetD32Async((hipDeviceptr_t)h_hist, (int)SENT,
                          (size_t)(SEQ + 1) * HSZ, stream);
  (void)hipMemsetAsync(h_hist, 0, HSZ * sizeof(float), stream);
  (void)hipMemsetAsync(fring, 0, (size_t)8 * 4 * 8 * 64 * sizeof(u64), stream);
  (void)hipMemsetAsync(elect, 0, 8 * sizeof(int), stream);
  (void)hipMemsetAsync(elect + 8, 0xFF, sizeof(int), stream); // winner = -1
  (void)hipMemsetAsync(elect + 9, 0, sizeof(int), stream);    // done = 0

  // Phase 1: P = x @ Wx^T + bh
  gemm_bt_bias<<<dim3(SEQ / 64, HSZ / 64), dim3(256), 0, stream>>>(
      x, Wx, bh, P, SEQ, HSZ, ISZ);

  // Phase 2: recurrence (8 same-XCD participants + 120 clock warmers)
  rnn_recur<<<dim3(NLAUNCH), dim3(RTHREADS), 0, stream>>>(
      P, Wh, h_hist, fring, elect);

  // Phase 3: y = h_hist[1..] @ Wy^T + by
  gemm_bt_bias<<<dim3(SEQ / 64, OSZ / 64), dim3(256), 0, stream>>>(
      h_hist + HSZ, Wy, by, out, SEQ, OSZ, HSZ);
}

// Round 5
// 30193.588 us; speedup vs baseline: 1.6097x; 1.0003x over previous
//
#include <hip/hip_runtime.h>

#define SEQ 32768
#define ISZ 256
#define HSZ 512
#define OSZ 256
#define NLAUNCH 64       // all 64 blocks run the XCD election; 8 winners persist
#define RTHREADS 512     // 8 waves: wave g is "home" (reduce+publish), rest poll
#define SENT 0x7FAAAAAAu // NaN sentinel for the slow (fabric) path
#define KFAST 8          // fast-poll iterations before falling back
#define LATCH_T 48       // fast-path verification window (steps)

typedef unsigned long long u64;
typedef _Float16 half2_t __attribute__((ext_vector_type(2)));

#if defined(__has_builtin)
#if __has_builtin(__builtin_amdgcn_fdot2)
#define HAVE_FDOT2 1
#endif
#endif

__device__ __forceinline__ float dot2f(half2_t a, half2_t b, float c) {
#ifdef HAVE_FDOT2
  return __builtin_amdgcn_fdot2(a, b, c, false);   // v_dot2_f32_f16
#else
  return fmaf((float)a.x, (float)b.x, fmaf((float)a.y, (float)b.y, c));
#endif
}
__device__ __forceinline__ half2_t bch2(unsigned u) {
  return __builtin_bit_cast(half2_t, u);
}
__device__ __forceinline__ unsigned pkrtz_u(float x, float y) {
  return __builtin_bit_cast(unsigned, __builtin_amdgcn_cvt_pkrtz(x, y));
}

// ---------------------------------------------------------------------------
// Generic tiled GEMM:  C[M,N] = A[M,K] @ W[N,K]^T + bias[N]   (unchanged)
// ---------------------------------------------------------------------------
__global__ __launch_bounds__(256) void gemm_bt_bias(
    const float* __restrict__ A, const float* __restrict__ W,
    const float* __restrict__ bias, float* __restrict__ C,
    int M, int N, int K)
{
  __shared__ float As[32][68];
  __shared__ float Bs[32][68];
  const int tx = threadIdx.x;
  const int tn = tx & 15, tm = tx >> 4;
  const int m0 = blockIdx.x * 64, n0 = blockIdx.y * 64;
  const int kl = tx & 31;
  const int rl = tx >> 5;
  float acc[4][4] = {};

  for (int kt = 0; kt < K; kt += 32) {
#pragma unroll
    for (int i = 0; i < 8; ++i) {
      int m = rl + i * 8;
      As[kl][m] = A[(size_t)(m0 + m) * K + kt + kl];
      Bs[kl][m] = W[(size_t)(n0 + m) * K + kt + kl];
    }
    __syncthreads();
#pragma unroll
    for (int k = 0; k < 32; ++k) {
      float a[4], b[4];
#pragma unroll
      for (int i = 0; i < 4; ++i) a[i] = As[k][tm * 4 + i];
#pragma unroll
      for (int j = 0; j < 4; ++j) b[j] = Bs[k][tn * 4 + j];
#pragma unroll
      for (int i = 0; i < 4; ++i)
#pragma unroll
        for (int j = 0; j < 4; ++j)
          acc[i][j] = fmaf(a[i], b[j], acc[i][j]);
    }
    __syncthreads();
  }
#pragma unroll
  for (int i = 0; i < 4; ++i) {
    int m = m0 + tm * 4 + i;
#pragma unroll
    for (int j = 0; j < 4; ++j) {
      int n = n0 + tn * 4 + j;
      C[(size_t)m * N + n] = acc[i][j] + bias[n];
    }
  }
}

// Slow path (r10-proven): 2-deep pipelined sentinel poll, fabric-coherent.
__device__ __forceinline__ float poll_sent(const float* p, unsigned sent) {
  float a, b;
  asm volatile(
      "s_waitcnt vmcnt(0)\n\t"
      "global_load_dword %0, %2, off sc0 sc1\n\t"
      "global_load_dword %1, %2, off sc0 sc1\n"
      "1:\n\t"
      "s_waitcnt vmcnt(1)\n\t"
      "v_cmp_eq_u32 vcc, %3, %0\n\t"
      "s_cbranch_vccz 3f\n\t"
      "global_load_dword %0, %2, off sc0 sc1\n\t"
      "s_waitcnt vmcnt(1)\n\t"
      "v_cmp_eq_u32 vcc, %3, %1\n\t"
      "s_cbranch_vccz 2f\n\t"
      "global_load_dword %1, %2, off sc0 sc1\n\t"
      "s_branch 1b\n"
      "2:\n\t"
      "v_mov_b32 %0, %1\n"
      "3:\n\t"
      "s_waitcnt vmcnt(0)"
      : "=&v"(a), "=&v"(b)
      : "v"(p), "v"(sent)
      : "memory", "vcc");
  return a;
}

// Fast path: sc0-only (L1-bypass, L2-scope). With the runtime election all
// participants are provably on one XCD. Bounded K + sentinel fallback keeps
// correctness placement-independent. NOTE: vmcnt(0) here is PER-WAVE -- it
// drains only this consumer's poll loads, never the home wave's prefetch.
__device__ __forceinline__ u64 load_fast(const u64* p) {
  u64 v;
  asm volatile("global_load_dwordx2 %0, %1, off sc0\n\t"
               "s_waitcnt vmcnt(0)"
               : "=v"(v) : "v"(p) : "memory");
  return v;
}
__device__ __forceinline__ void store_fast(u64* p, u64 v) {
  asm volatile("global_store_dwordx2 %0, %1, off sc0" :: "v"(p), "v"(v)
               : "memory");
}

// ---------------------------------------------------------------------------
// Persistent recurrence, ROUND-17: raw barrier -- NEVER drain vmcnt in-loop.
//
// r16 post-mortem: clock theory falsified (warmers ran at VALUBusy 41%,
// zero speedup -> removed). Re-audit found the missing ~1000cy of the step:
// __syncthreads makes the compiler emit s_waitcnt vmcnt(0) lgkmcnt(0)
// before s_barrier (documented HIP-compiler behavior). The home wave's
// epilogue issues a ~900cy HBM P-prefetch + 9 stores, then hits the next
// barrier ~300cy later -> ~600-700cy forced drain EVERY step, with all 7
// consumer waves held at the barrier behind it. Leg-sum with this drain
// matches the measured 2175cy/step; without it, ~1250-1500cy.
//
// Fix (T4 applied to a latency chain): replace the loop __syncthreads with
//   s_waitcnt lgkmcnt(0); s_barrier      (inline asm, memory clobber)
// LDS partial writes are committed (lgkmcnt only); the home wave's P-load
// and publish stores stay IN FLIGHT across the barrier. The P-load's only
// wait is the compiler's vmcnt before its use, a full step (~1300cy) after
// issue -> HBM latency fully hidden. vmcnt is per-wave, so consumer polls
// are unaffected. Double-buffered part[] keeps LDS races impossible; ring
// slot-reuse causality unchanged (4-step spacing, dense coupling).
// ---------------------------------------------------------------------------
__global__ __launch_bounds__(RTHREADS, 2) void rnn_recur(
    const float* __restrict__ P,     // [SEQ][HSZ]
    const float* __restrict__ Wh,    // [HSZ][HSZ]
    float* __restrict__ h_hist,      // [SEQ+1][HSZ]; row0=0, rows 1..=SENT
    u64* __restrict__ fring,         // [8 consumerWG][4 slot][8 chunk][64]
    int* __restrict__ elect)         // [0..7]=per-XCD count, [8]=winner (-1)
{
  const int tid = threadIdx.x;
  const int w = tid >> 6;            // wave 0..7
  const int l = tid & 63;

  __shared__ float part[2][8][64];   // [buf][wave][lane] - conflict-free
  __shared__ int s_role;

  // -------- one-time election (tid 0 of every block) --------
  if (tid == 0) {
    unsigned xcc;
    asm volatile("s_getreg_b32 %0, hwreg(HW_REG_XCC_ID)" : "=s"(xcc));
    xcc &= 7u;
    int role = -1;
    int r = __hip_atomic_fetch_add(&elect[xcc], 1, __ATOMIC_RELAXED,
                                   __HIP_MEMORY_SCOPE_AGENT);
    if (r < 8) {
      if (r == 7) {                  // 8th block on this XCD: declare winner
        int exp_ = -1;
        (void)__hip_atomic_compare_exchange_strong(
            &elect[8], &exp_, (int)xcc,
            __ATOMIC_RELEASE, __ATOMIC_RELAXED, __HIP_MEMORY_SCOPE_AGENT);
      }
      int wv;
      do {
        wv = __hip_atomic_load(&elect[8], __ATOMIC_ACQUIRE,
                               __HIP_MEMORY_SCOPE_AGENT);
      } while (wv < 0);              // guaranteed: pigeonhole 64 blocks / 8 XCDs
      if (wv == (int)xcc) role = r;  // ranks 0..7 on winner XCD participate
    }
    s_role = role;
  }
  __syncthreads();                   // prologue only (full semantics fine here)
  const int g = s_role;              // participant id 0..7, or -1
  if (g < 0) return;

  const int g64 = g << 6;
  const int row = g64 + l;           // block owns output rows [g64, g64+64)
  const int kbase = w << 6;          // wave owns k-chunk w

  // Lane's 64 weights, f16-packed: 32 half2 regs (r10-proven dot).
  unsigned wreg[32];
  {
    const float2* ws = (const float2*)(Wh + (size_t)row * HSZ + kbase);
#pragma unroll
    for (int j = 0; j < 32; ++j) {
      float2 f = ws[j];
      unsigned u = pkrtz_u(f.x, f.y);
      asm("" : "+v"(u));
      wreg[j] = u;
    }
  }

  const bool home = (w == g);        // home wave: chunk g lives in hreg
  float hreg = 0.f;                  // h[t][row] for home wave (h[0]=0)
  float pv = home ? P[row] : 0.f;    // P[t], prefetched one step ahead
  float pvn = 0.f;
  int fastok = 0, use_fast = 1;

  for (int t = 0; t < SEQ; ++t) {
    float vh = 0.f;
    if (home) {
      vh = hreg;                     // register-local, zero-latency
    } else if (t > 0) {
      int got = 0;
      if (use_fast) {
        const u64* fp = fring + (((size_t)g * 4 + (t & 3)) * 8 + w) * 64 + l;
        for (int k = 0; k < KFAST; ++k) {
          u64 v = load_fast(fp);
          if (__all((int)((unsigned)(v >> 32) == (unsigned)t))) {
            vh = __uint_as_float((unsigned)v);
            got = 1;
            break;
          }
        }
        if (t <= LATCH_T) {
          fastok += got;
          if (t == LATCH_T && fastok < LATCH_T - 8) use_fast = 0;
        }
      }
      if (!got)
        vh = poll_sent(h_hist + (size_t)t * HSZ + kbase + l, SENT);
    }

    // Pack h to f16 pairs; 32 readlane + 32 dot2, 4 accumulator chains.
    float vn = __shfl_xor(vh, 1);
    unsigned hpu = pkrtz_u(vh, vn);
    float a0 = 0.f, a1 = 0.f, a2 = 0.f, a3 = 0.f;
#pragma unroll
    for (int j = 0; j < 8; ++j) {
      a0 = dot2f(bch2(wreg[4 * j + 0]),
                 bch2(__builtin_amdgcn_readlane(hpu, 8 * j + 0)), a0);
      a1 = dot2f(bch2(wreg[4 * j + 1]),
                 bch2(__builtin_amdgcn_readlane(hpu, 8 * j + 2)), a1);
      a2 = dot2f(bch2(wreg[4 * j + 2]),
                 bch2(__builtin_amdgcn_readlane(hpu, 8 * j + 4)), a2);
      a3 = dot2f(bch2(wreg[4 * j + 3]),
                 bch2(__builtin_amdgcn_readlane(hpu, 8 * j + 6)), a3);
    }
    part[t & 1][w][l] = (a0 + a1) + (a2 + a3);

    // Raw barrier: commit LDS writes (lgkmcnt only), do NOT drain vmcnt --
    // the home wave's P-prefetch and publish stores stay in flight.
    asm volatile("s_waitcnt lgkmcnt(0)\n\ts_barrier" ::: "memory");

    if (home) {
      __builtin_amdgcn_s_setprio(1); // serial segment: favor this wave
      // P prefetch for t+1: issued first for max slack; waited only at its
      // use in the NEXT epilogue (~full step later) -> HBM latency hidden.
      pvn = P[(size_t)(t + 1 < SEQ ? t + 1 : SEQ - 1) * HSZ + row];
      const int buf = t & 1;
      float p0 = part[buf][0][l], p1 = part[buf][1][l];
      float p2 = part[buf][2][l], p3 = part[buf][3][l];
      float p4 = part[buf][4][l], p5 = part[buf][5][l];
      float p6 = part[buf][6][l], p7 = part[buf][7][l];
      float s = ((p0 + p1) + (p2 + p3)) + ((p4 + p5) + (p6 + p7));
      float xv = s + pv;
      xv = fminf(fmaxf(xv, -15.f), 15.f);
      float e = __expf(2.f * xv);
      float hn = fmaf(-2.f, __builtin_amdgcn_rcpf(e + 1.f), 1.f); // tanh(xv)
      hreg = hn;
      // Fast publish FIRST (consumer-visible path), tagged {step,val}.
      const u64 pk = ((u64)(unsigned)(t + 1) << 32) | (u64)__float_as_uint(hn);
      const int slot = (t + 1) & 3;
#pragma unroll
      for (int j = 0; j < 8; ++j)
        store_fast(fring + (((size_t)j * 4 + slot) * 8 + g) * 64 + l, pk);
      // Slow-path + final-output publish (fabric; value IS the signal).
      __hip_atomic_store(&h_hist[(size_t)(t + 1) * HSZ + row], hn,
                         __ATOMIC_RELAXED, __HIP_MEMORY_SCOPE_AGENT);
      pv = pvn;
      __builtin_amdgcn_s_setprio(0);
    }
  }
}

// ---------------------------------------------------------------------------
extern "C" void kernel_launch(void* const* d_in, const int* in_sizes, int n_in,
                              void* d_out, int out_size, void* d_ws, size_t ws_size,
                              hipStream_t stream) {
  const float* x  = (const float*)d_in[0];  // [SEQ][ISZ]
  const float* Wx = (const float*)d_in[1];  // [HSZ][ISZ]
  const float* Wh = (const float*)d_in[2];  // [HSZ][HSZ]
  const float* Wy = (const float*)d_in[3];  // [OSZ][HSZ]
  const float* bh = (const float*)d_in[4];  // [HSZ]
  const float* by = (const float*)d_in[5];  // [OSZ]
  float* out = (float*)d_out;               // [SEQ][OSZ]

  float* P      = (float*)d_ws;             // SEQ*HSZ      (64 MB)
  float* h_hist = P + (size_t)SEQ * HSZ;    // (SEQ+1)*HSZ  (64 MB)
  u64*   fring  = (u64*)(h_hist + (size_t)(SEQ + 1) * HSZ); // 128 KB
  int*   elect  = (int*)(fring + (size_t)8 * 4 * 8 * 64);   // 9 ints

  // Sentinel-fill h_hist (slow path), zero row 0; zero fring tags; reset
  // election state (counts=0, winner=-1) every replay.
  (void)hipMemsetD32Async((hipDeviceptr_t)h_hist, (int)SENT,
                          (size_t)(SEQ + 1) * HSZ, stream);
  (void)hipMemsetAsync(h_hist, 0, HSZ * sizeof(float), stream);
  (void)hipMemsetAsync(fring, 0, (size_t)8 * 4 * 8 * 64 * sizeof(u64), stream);
  (void)hipMemsetAsync(elect, 0, 8 * sizeof(int), stream);
  (void)hipMemsetAsync(elect + 8, 0xFF, sizeof(int), stream); // winner = -1

  // Phase 1: P = x @ Wx^T + bh
  gemm_bt_bias<<<dim3(SEQ / 64, HSZ / 64), dim3(256), 0, stream>>>(
      x, Wx, bh, P, SEQ, HSZ, ISZ);

  // Phase 2: recurrence (8 same-XCD participants, elected at runtime)
  rnn_recur<<<dim3(NLAUNCH), dim3(RTHREADS), 0, stream>>>(
      P, Wh, h_hist, fring, elect);

  // Phase 3: y = h_hist[1..] @ Wy^T + by
  gemm_bt_bias<<<dim3(SEQ / 64, OSZ / 64), dim3(256), 0, stream>>>(
      h_hist + HSZ, Wy, by, out, SEQ, OSZ, HSZ);
}